// Round 3
// baseline (22488.551 us; speedup 1.0000x reference)
//
#include <hip/hip_runtime.h>
#include <hip/hip_bf16.h>

// Problem constants
#define B_   32
#define T_   2000
#define H_   896
#define SUB_ 448
#define Q_   256

// d_out layout (floats): ct [32,2000,256], ft [32,2000,256], last [32,1,896]
#define FT_OFF   16384000
#define LAST_OFF 32768000

// scan decomposition: 28 blocks x 192 threads (3 waves, 1 wave/SIMD)
#define NBLK_ 28

// d_ws layout (bytes)
//   flags  : [56] ints padded x32 (128B apart)        @ 0       (7168 B)
//   h0     : bf16 [32][896]                           @ 8192    (57344 B)
//   Wb     : bf16 W1c|W1f|W2c|W2f                     @ 65536   (1261568 B)
//   states : bf16 time-major [2000][32][896]          @ 1327104 (114688000 B)
#define WS_FLAGS  0
#define WS_H0     8192
#define WS_WB     65536
#define WS_STATES 1327104

// Wb element offsets (ushort units)
#define WB_W1C 0
#define WB_W1F 200704
#define WB_W2C 401408
#define WB_W2F 516096
#define WB_N   630784

#define SLOT_B 57344   // bytes per states time-slot (32*896*2)
#define SLOT_E 28672   // ushort elems per slot

typedef __attribute__((ext_vector_type(8)))  short bf16x8;
typedef __attribute__((ext_vector_type(16))) float f32x16;

__device__ __forceinline__ unsigned short f2bf(float f) {
    unsigned int u = __builtin_bit_cast(unsigned int, f);
    u += 0x7fff + ((u >> 16) & 1);          // RNE
    return (unsigned short)(u >> 16);
}
__device__ __forceinline__ float bf2f(unsigned short u) {
    return __builtin_bit_cast(float, (unsigned int)u << 16);
}
__device__ __forceinline__ void gload_lds4(const void* g, void* l) {
    __builtin_amdgcn_global_load_lds(
        (const __attribute__((address_space(1))) unsigned int*)g,
        (__attribute__((address_space(3))) unsigned int*)l, 4, 0, 0);
}
__device__ __forceinline__ bf16x8 mk8(short4 a, short4 b) {
    bf16x8 f;
    f[0]=a.x; f[1]=a.y; f[2]=a.z; f[3]=a.w;
    f[4]=b.x; f[5]=b.y; f[6]=b.z; f[7]=b.w;
    return f;
}
__device__ __forceinline__ float fsig(float x) {
    return __builtin_amdgcn_rcpf(1.0f + __expf(-x));
}
__device__ __forceinline__ float ftanh(float x) {
    float xc = fminf(fmaxf(x, -9.0f), 9.0f);
    float z  = __expf(2.0f * xc);
    return 1.0f - 2.0f * __builtin_amdgcn_rcpf(z + 1.0f);
}

// ---------------------------------------------------------------------------
// prep: flags=0, h0=bf16(state), Wb=bf16(W1c|W1f|W2c|W2f)
// ---------------------------------------------------------------------------
__global__ void wavrnn_prep(const float* __restrict__ state,
                            const float* __restrict__ Wc1, const float* __restrict__ Wf1,
                            const float* __restrict__ Wc2, const float* __restrict__ Wf2,
                            unsigned short* __restrict__ wb,
                            unsigned short* __restrict__ h0,
                            int* __restrict__ flags) {
    const int i = blockIdx.x * 256 + threadIdx.x;
    if (i < WB_N) {
        float v;
        if      (i < WB_W1F) v = Wc1[i];
        else if (i < WB_W2C) v = Wf1[i - WB_W1F];
        else if (i < WB_W2F) v = Wc2[i - WB_W2C];
        else                 v = Wf2[i - WB_W2F];
        wb[i] = f2bf(v);
    }
    if (i < 1792) flags[i] = 0;
    if (i < B_ * H_) h0[i] = f2bf(state[i]);
}

// ---------------------------------------------------------------------------
// scan v3: register-resident R (bf16 B-frags), rotated-LDS A staging,
// fence-free IF$ exchange through time-major states, per-wave flags.
// ---------------------------------------------------------------------------
__global__ __launch_bounds__(192, 1)
void wavrnn_scan3(const int* __restrict__ sample, const int* __restrict__ cts,
                  const float* __restrict__ state, const float* __restrict__ R,
                  const float* __restrict__ Wc, const float* __restrict__ Wf,
                  const float* __restrict__ b_u, const float* __restrict__ b_r,
                  const float* __restrict__ b_e,
                  const unsigned short* __restrict__ h0,
                  int* __restrict__ flags,
                  unsigned short* __restrict__ states,   // time-major [2000][32][896]
                  float* __restrict__ out)
{
    const int tid  = (int)threadIdx.x;
    const int w    = tid >> 6;        // wave = gate (0:u, 1:r, 2:e)
    const int lane = tid & 63;
    const int s31  = lane & 31;
    const int hi   = lane >> 5;
    const int b    = (int)blockIdx.x;

    // rotated h tile: row s at [s*2048, +2048); element k at 8*s + 2*k (no wrap)
    __shared__ __align__(16) char Abuf[32 * 2048];     // 65536
    __shared__ float gate_out[3][32][34];              // 13056

    // ---- register-resident B fragments (verified v2 layout) ----
    const int jgB = b * 32 + s31;
    bf16x8 Bf[56];
    {
        const float* Rrow = R + (size_t)(w * H_ + jgB) * H_;
        #pragma unroll
        for (int c = 0; c < 56; ++c) {
            const float4 p0 = *(const float4*)(Rrow + 16*c + 4*hi);
            const float4 p1 = *(const float4*)(Rrow + 16*c + 8 + 4*hi);
            bf16x8 f;
            f[0]=(short)f2bf(p0.x); f[1]=(short)f2bf(p0.y);
            f[2]=(short)f2bf(p0.z); f[3]=(short)f2bf(p0.w);
            f[4]=(short)f2bf(p1.x); f[5]=(short)f2bf(p1.y);
            f[6]=(short)f2bf(p1.z); f[7]=(short)f2bf(p1.w);
            Bf[c] = f;
        }
    }

    // ---- gate-thread constants (tid<128): 2 j x 4 s per thread ----
    const int jp  = tid & 15;
    const int sg  = (tid >> 4) & 7;
    const int j0  = 2 * jp;
    const int jg0 = b * 32 + j0;
    float wu[2][3], wr[2][3], we[2][3], gb[2][3];
    float hreg[4][2];
    if (tid < 128) {
        #pragma unroll
        for (int jj = 0; jj < 2; ++jj) {
            const int jg = jg0 + jj;
            if (jg < SUB_) {
                wu[jj][0]=Wc[2*jg];            wu[jj][1]=Wc[2*jg+1];            wu[jj][2]=0.f;
                wr[jj][0]=Wc[2*(SUB_+jg)];     wr[jj][1]=Wc[2*(SUB_+jg)+1];     wr[jj][2]=0.f;
                we[jj][0]=Wc[2*(2*SUB_+jg)];   we[jj][1]=Wc[2*(2*SUB_+jg)+1];   we[jj][2]=0.f;
            } else {
                const int jf = jg - SUB_;
                wu[jj][0]=Wf[3*jf];            wu[jj][1]=Wf[3*jf+1];            wu[jj][2]=Wf[3*jf+2];
                wr[jj][0]=Wf[3*(SUB_+jf)];     wr[jj][1]=Wf[3*(SUB_+jf)+1];     wr[jj][2]=Wf[3*(SUB_+jf)+2];
                we[jj][0]=Wf[3*(2*SUB_+jf)];   we[jj][1]=Wf[3*(2*SUB_+jf)+1];   we[jj][2]=Wf[3*(2*SUB_+jf)+2];
            }
            gb[jj][0]=b_u[jg]; gb[jj][1]=b_r[jg]; gb[jj][2]=b_e[jg];
        }
        #pragma unroll
        for (int q = 0; q < 4; ++q) {
            const int s = sg*4 + q;
            hreg[q][0] = state[(size_t)s*H_ + jg0];
            hreg[q][1] = state[(size_t)s*H_ + jg0 + 1];
        }
    }

    const int v4l = lane * 4;
    const char* abb = Abuf + s31*2048 + 8*s31 + 8*hi;   // A-frag base (imm + 32c)

    #pragma unroll 1
    for (int t = 1; t <= T_; ++t) {
        // ---- (A) per-step inputs (issued before spin; latency hidden) ----
        float s0n[4], s1n[4], c0n[4];
        if (tid < 128) {
            const float kn = 2.0f / 255.0f;
            #pragma unroll
            for (int q = 0; q < 4; ++q) {
                const size_t idx = (size_t)(sg*4 + q)*T_ + (size_t)(t - 1);
                const int2 sv = *(const int2*)(sample + idx*2);
                s0n[q] = kn*(float)sv.x - 1.0f;
                s1n[q] = kn*(float)sv.y - 1.0f;
                c0n[q] = kn*(float)cts[idx] - 1.0f;
            }
        }
        // ---- (B) spin: all waves poll 56 padded sub-flags (no fence) ----
        for (;;) {
            int v = (lane < 56)
                ? __hip_atomic_load(&flags[lane*32], __ATOMIC_RELAXED, __HIP_MEMORY_SCOPE_AGENT)
                : 0x7fffffff;
            if (__all(v >= t - 1)) break;
        }
        asm volatile("" ::: "memory");
        __builtin_amdgcn_sched_barrier(0);

        // ---- (C) stage h(t-1) rotated into LDS, 4B granularity, coalesced ----
        {
            const char* sb = (t == 1) ? (const char*)h0
                                      : (const char*)states + (size_t)(t - 2)*SLOT_B;
            #pragma unroll
            for (int ii = 0; ii < 86; ++ii) {
                const int i = w + 3*ii;
                if (i < 256) {
                    const int sp = i >> 3;
                    // src = sb + 1792*sp + (o - 8*sp), o = 256*(i&7) + 4*lane
                    gload_lds4(sb + sp*1784 + (i & 7)*256 + v4l, Abuf + i*256);
                }
            }
        }
        __syncthreads();   // (D) staging complete

        // ---- (E) MFMA, dual accumulator chains ----
        f32x16 acc0, acc1;
        #pragma unroll
        for (int e = 0; e < 16; ++e) { acc0[e] = 0.0f; acc1[e] = 0.0f; }
        #pragma unroll
        for (int c2 = 0; c2 < 28; ++c2) {
            {
                const short4 p0 = *(const short4*)(abb + 64*c2);
                const short4 p1 = *(const short4*)(abb + 64*c2 + 16);
                acc0 = __builtin_amdgcn_mfma_f32_32x32x16_bf16(mk8(p0, p1), Bf[2*c2], acc0, 0, 0, 0);
            }
            {
                const short4 p0 = *(const short4*)(abb + 64*c2 + 32);
                const short4 p1 = *(const short4*)(abb + 64*c2 + 48);
                acc1 = __builtin_amdgcn_mfma_f32_32x32x16_bf16(mk8(p0, p1), Bf[2*c2+1], acc1, 0, 0, 0);
            }
        }
        #pragma unroll
        for (int e = 0; e < 16; ++e) {
            const int srow = (e & 3) + 8*(e >> 2) + 4*hi;
            gate_out[w][srow][s31] = acc0[e] + acc1[e];
        }
        __syncthreads();   // (F)

        // ---- (G) gates + h update ----
        if (tid < 128) {
            #pragma unroll
            for (int q = 0; q < 4; ++q) {
                const int s = sg*4 + q;
                const float2 g0 = *(const float2*)&gate_out[0][s][j0];
                const float2 g1 = *(const float2*)&gate_out[1][s][j0];
                const float2 g2 = *(const float2*)&gate_out[2][s][j0];
                unsigned int packed = 0;
                #pragma unroll
                for (int jj = 0; jj < 2; ++jj) {
                    const float ru = jj ? g0.y : g0.x;
                    const float rr = jj ? g1.y : g1.x;
                    const float re = jj ? g2.y : g2.x;
                    const float fu = s0n[q]*wu[jj][0] + s1n[q]*wu[jj][1] + c0n[q]*wu[jj][2];
                    const float fr = s0n[q]*wr[jj][0] + s1n[q]*wr[jj][1] + c0n[q]*wr[jj][2];
                    const float fe = s0n[q]*we[jj][0] + s1n[q]*we[jj][1] + c0n[q]*we[jj][2];
                    const float ut = fsig(ru + fu + gb[jj][0]);
                    const float rt = fsig(rr + fr + gb[jj][1]);
                    const float et = ftanh(rt*re + fe + gb[jj][2]);
                    const float hn = ut*hreg[q][jj] + (1.0f - ut)*et;
                    hreg[q][jj] = hn;
                    packed |= (unsigned int)f2bf(hn) << (16*jj);
                    if (t == T_) out[LAST_OFF + (size_t)s*H_ + jg0 + jj] = hn;
                }
                __hip_atomic_store(
                    (unsigned int*)(states + (size_t)(t-1)*SLOT_E + s*H_ + jg0),
                    packed, __ATOMIC_RELAXED, __HIP_MEMORY_SCOPE_AGENT);
            }
        }
        // ---- (H) own-wave store drain, then per-wave flag ----
        if (w < 2) {
            asm volatile("s_waitcnt vmcnt(0)" ::: "memory");
            if (lane == 0)
                __hip_atomic_store(&flags[(2*b + w)*32], t,
                                   __ATOMIC_RELAXED, __HIP_MEMORY_SCOPE_AGENT);
        }
    }
}

// ---------------------------------------------------------------------------
// head v3 (MFMA bf16): per block 32 rows; relu(W1 h + b1) -> W2 + b2 -> log_softmax
// ---------------------------------------------------------------------------
__global__ __launch_bounds__(256, 1)
void wavrnn_head3(const unsigned short* __restrict__ states,  // time-major
                  const unsigned short* __restrict__ wb,
                  const float* __restrict__ bc1, const float* __restrict__ bc2,
                  const float* __restrict__ bf1, const float* __restrict__ bf2,
                  float* __restrict__ out)
{
    // rotated rows, pitch 1920, rotation 8*(row&15)
    __shared__ __align__(16) char stL[32 * 1920];   // 61440 (aliased by lg after stage A)
    __shared__ __align__(16) char a1L[32 * 1920];   // 61440

    const int tid  = (int)threadIdx.x;
    const int w    = tid >> 6;
    const int lane = tid & 63;
    const int nl   = lane & 31;
    const int hi   = lane >> 5;
    const int row0 = (int)blockIdx.x * 32;

    // ---- stage states rows (8B pieces, rotated) ----
    #pragma unroll
    for (int ii = 0; ii < 28; ++ii) {
        const int idx = ii*256 + tid;        // 0..7167 = 32 rows x 224 pieces
        const int rp  = idx / 224;
        const int p   = idx - rp*224;
        const int r   = row0 + rp;
        const int sr  = r / 2000;
        const int tr  = r - sr*2000;
        const uint2 v = *(const uint2*)(states + (size_t)tr*SLOT_E + sr*H_ + p*4);
        *(uint2*)(stL + rp*1920 + 8*(rp & 15) + p*8) = v;
    }
    __syncthreads();

    // ---- stage A: a1 = relu(W1 h_half + b1); 28 n-tiles over 4 waves ----
    {
        const char* apb = stL + nl*1920 + 8*(nl & 15) + 8*hi;
        #pragma unroll 1
        for (int tt = 0; tt < 7; ++tt) {
            const int nt   = tt*4 + w;
            const int head = nt >= 14;
            const int jt   = nt - head*14;
            const int orow = jt*32 + nl;                     // 0..447
            const unsigned short* wrp = wb + (head ? WB_W1F : WB_W1C) + (size_t)orow*448;
            const float bias = (head ? bf1 : bc1)[orow];
            const int ko = head * 896;
            f32x16 acc;
            #pragma unroll
            for (int e = 0; e < 16; ++e) acc[e] = bias;
            #pragma unroll
            for (int c = 0; c < 28; ++c) {
                const short4 a0 = *(const short4*)(apb + ko + 32*c);
                const short4 a1 = *(const short4*)(apb + ko + 32*c + 16);
                const short4 b0 = *(const short4*)((const char*)wrp + 32*c + 8*hi);
                const short4 b1 = *(const short4*)((const char*)wrp + 32*c + 8*hi + 16);
                acc = __builtin_amdgcn_mfma_f32_32x32x16_bf16(mk8(a0, a1), mk8(b0, b1), acc, 0, 0, 0);
            }
            const int jg = head*448 + jt*32 + nl;
            #pragma unroll
            for (int e = 0; e < 16; ++e) {
                const int m2 = (e & 3) + 8*(e >> 2) + 4*hi;
                *(unsigned short*)(a1L + m2*1920 + 8*(m2 & 15) + 2*jg) =
                    f2bf(fmaxf(acc[e], 0.0f));
            }
        }
    }
    __syncthreads();

    // ---- stage B: logits = W2 a1_half + b2 -> lg (bf16, aliases stL) ----
    {
        unsigned short* lg = (unsigned short*)stL;    // [32][520]
        const char* apb = a1L + nl*1920 + 8*(nl & 15) + 8*hi;
        #pragma unroll 1
        for (int tt = 0; tt < 4; ++tt) {
            const int nt   = tt*4 + w;
            const int head = nt >= 8;
            const int ct   = (nt & 7)*32 + nl;               // 0..255
            const unsigned short* wrp = wb + (head ? WB_W2F : WB_W2C) + (size_t)ct*448;
            const float bias = (head ? bf2 : bc2)[ct];
            const int ko = head * 896;
            f32x16 acc;
            #pragma unroll
            for (int e = 0; e < 16; ++e) acc[e] = bias;
            #pragma unroll
            for (int c = 0; c < 28; ++c) {
                const short4 a0 = *(const short4*)(apb + ko + 32*c);
                const short4 a1 = *(const short4*)(apb + ko + 32*c + 16);
                const short4 b0 = *(const short4*)((const char*)wrp + 32*c + 8*hi);
                const short4 b1 = *(const short4*)((const char*)wrp + 32*c + 8*hi + 16);
                acc = __builtin_amdgcn_mfma_f32_32x32x16_bf16(mk8(a0, a1), mk8(b0, b1), acc, 0, 0, 0);
            }
            #pragma unroll
            for (int e = 0; e < 16; ++e) {
                const int m2 = (e & 3) + 8*(e >> 2) + 4*hi;
                lg[m2*520 + head*256 + (nt & 7)*32 + nl] = f2bf(acc[e]);
            }
        }
    }
    __syncthreads();

    // ---- log_softmax per (head,row) ----
    {
        const unsigned short* lg = (const unsigned short*)stL;
        #pragma unroll 1
        for (int p = w; p < 64; p += 4) {
            const int hh = p >> 5;
            const int rr = p & 31;
            const ushort4 lv = *(const ushort4*)(lg + rr*520 + hh*256 + 4*lane);
            const float v0 = bf2f(lv.x), v1 = bf2f(lv.y), v2 = bf2f(lv.z), v3 = bf2f(lv.w);
            float m = fmaxf(fmaxf(v0, v1), fmaxf(v2, v3));
            #pragma unroll
            for (int d = 1; d < 64; d <<= 1) m = fmaxf(m, __shfl_xor(m, d));
            float sm = __expf(v0-m) + __expf(v1-m) + __expf(v2-m) + __expf(v3-m);
            #pragma unroll
            for (int d = 1; d < 64; d <<= 1) sm += __shfl_xor(sm, d);
            const float ls = m + __logf(sm);
            float* o = out + (hh ? (size_t)FT_OFF : (size_t)0) + (size_t)(row0 + rr)*Q_ + 4*lane;
            o[0] = v0 - ls; o[1] = v1 - ls; o[2] = v2 - ls; o[3] = v3 - ls;
        }
    }
}

// ---------------------------------------------------------------------------
extern "C" void kernel_launch(void* const* d_in, const int* in_sizes, int n_in,
                              void* d_out, int out_size, void* d_ws, size_t ws_size,
                              hipStream_t stream) {
    (void)in_sizes; (void)n_in; (void)out_size; (void)ws_size;
    const int*   sample = (const int*)d_in[0];
    const int*   cts    = (const int*)d_in[1];
    const float* state  = (const float*)d_in[2];
    const float* R      = (const float*)d_in[3];
    const float* Wc     = (const float*)d_in[4];
    const float* Wf     = (const float*)d_in[5];
    const float* b_u    = (const float*)d_in[6];
    const float* b_r    = (const float*)d_in[7];
    const float* b_e    = (const float*)d_in[8];
    const float* Wc1    = (const float*)d_in[9];
    const float* bc1    = (const float*)d_in[10];
    const float* Wc2    = (const float*)d_in[11];
    const float* bc2    = (const float*)d_in[12];
    const float* Wf1    = (const float*)d_in[13];
    const float* bf1    = (const float*)d_in[14];
    const float* Wf2    = (const float*)d_in[15];
    const float* bf2    = (const float*)d_in[16];

    float* out = (float*)d_out;
    int*            flags  = (int*)((char*)d_ws + WS_FLAGS);
    unsigned short* h0     = (unsigned short*)((char*)d_ws + WS_H0);
    unsigned short* wb     = (unsigned short*)((char*)d_ws + WS_WB);
    unsigned short* states = (unsigned short*)((char*)d_ws + WS_STATES);

    wavrnn_prep<<<2464, 256, 0, stream>>>(state, Wc1, Wf1, Wc2, Wf2, wb, h0, flags);
    wavrnn_scan3<<<NBLK_, 192, 0, stream>>>(sample, cts, state, R, Wc, Wf,
                                            b_u, b_r, b_e, h0, flags, states, out);
    wavrnn_head3<<<(B_ * T_) / 32, 256, 0, stream>>>(states, wb, bc1, bc2, bf1, bf2, out);
}

// Round 4
// 21942.581 us; speedup vs baseline: 1.0249x; 1.0249x over previous
//
#include <hip/hip_runtime.h>
#include <hip/hip_bf16.h>

// Problem constants
#define B_   32
#define T_   2000
#define H_   896
#define SUB_ 448
#define Q_   256

// d_out layout (floats): ct [32,2000,256], ft [32,2000,256], last [32,1,896]
#define FT_OFF   16384000
#define LAST_OFF 32768000

// scan decomposition: 28 blocks x 192 threads (3 waves, 1 wave/SIMD)
#define NBLK_ 28

// d_ws layout (bytes)
//   counter: int epoch counter (alone in cacheline)   @ 0
//   h0     : bf16 [32][896]                           @ 8192    (57344 B)
//   Wb     : bf16 W1c|W1f|W2c|W2f                     @ 65536   (1261568 B)
//   states : bf16 time-major [2000][32][896]          @ 1327104 (114688000 B)
#define WS_FLAGS  0
#define WS_H0     8192
#define WS_WB     65536
#define WS_STATES 1327104

// Wb element offsets (ushort units)
#define WB_W1C 0
#define WB_W1F 200704
#define WB_W2C 401408
#define WB_W2F 516096
#define WB_N   630784

#define SLOT_B 57344   // bytes per states time-slot (32*896*2)
#define SLOT_E 28672   // ushort elems per slot

typedef __attribute__((ext_vector_type(8)))  short bf16x8;
typedef __attribute__((ext_vector_type(16))) float f32x16;

__device__ __forceinline__ unsigned short f2bf(float f) {
    unsigned int u = __builtin_bit_cast(unsigned int, f);
    u += 0x7fff + ((u >> 16) & 1);          // RNE
    return (unsigned short)(u >> 16);
}
__device__ __forceinline__ float bf2f(unsigned short u) {
    return __builtin_bit_cast(float, (unsigned int)u << 16);
}
__device__ __forceinline__ void gload_lds4(const void* g, void* l) {
    __builtin_amdgcn_global_load_lds(
        (const __attribute__((address_space(1))) unsigned int*)g,
        (__attribute__((address_space(3))) unsigned int*)l, 4, 0, 0);
}
__device__ __forceinline__ bf16x8 mk8(short4 a, short4 b) {
    bf16x8 f;
    f[0]=a.x; f[1]=a.y; f[2]=a.z; f[3]=a.w;
    f[4]=b.x; f[5]=b.y; f[6]=b.z; f[7]=b.w;
    return f;
}
__device__ __forceinline__ float fsig(float x) {
    return __builtin_amdgcn_rcpf(1.0f + __expf(-x));
}
__device__ __forceinline__ float ftanh(float x) {
    float xc = fminf(fmaxf(x, -9.0f), 9.0f);
    float z  = __expf(2.0f * xc);
    return 1.0f - 2.0f * __builtin_amdgcn_rcpf(z + 1.0f);
}

// ---------------------------------------------------------------------------
// prep: counter=0, h0=bf16(state), Wb=bf16(W1c|W1f|W2c|W2f)
// ---------------------------------------------------------------------------
__global__ void wavrnn_prep(const float* __restrict__ state,
                            const float* __restrict__ Wc1, const float* __restrict__ Wf1,
                            const float* __restrict__ Wc2, const float* __restrict__ Wf2,
                            unsigned short* __restrict__ wb,
                            unsigned short* __restrict__ h0,
                            int* __restrict__ flags) {
    const int i = blockIdx.x * 256 + threadIdx.x;
    if (i < WB_N) {
        float v;
        if      (i < WB_W1F) v = Wc1[i];
        else if (i < WB_W2C) v = Wf1[i - WB_W1F];
        else if (i < WB_W2F) v = Wc2[i - WB_W2C];
        else                 v = Wf2[i - WB_W2F];
        wb[i] = f2bf(v);
    }
    if (i < 64) flags[i] = 0;
    if (i < B_ * H_) h0[i] = f2bf(state[i]);
}

// ---------------------------------------------------------------------------
// scan v4: v3 compute structure (rotated LDS, dual MFMA chains) with v2-style
// sync topology: single epoch counter, wave-0-only poll + s_sleep backoff.
// ---------------------------------------------------------------------------
__global__ __launch_bounds__(192, 1)
void wavrnn_scan4(const int* __restrict__ sample, const int* __restrict__ cts,
                  const float* __restrict__ state, const float* __restrict__ R,
                  const float* __restrict__ Wc, const float* __restrict__ Wf,
                  const float* __restrict__ b_u, const float* __restrict__ b_r,
                  const float* __restrict__ b_e,
                  const unsigned short* __restrict__ h0,
                  int* __restrict__ counter,
                  unsigned short* __restrict__ states,   // time-major [2000][32][896]
                  float* __restrict__ out)
{
    const int tid  = (int)threadIdx.x;
    const int w    = tid >> 6;        // wave = gate (0:u, 1:r, 2:e)
    const int lane = tid & 63;
    const int s31  = lane & 31;
    const int hi   = lane >> 5;
    const int b    = (int)blockIdx.x;

    // rotated h tile: row s at [s*2048, +2048); element k at 8*s + 2*k (no wrap)
    __shared__ __align__(16) char Abuf[32 * 2048];     // 65536
    __shared__ float gate_out[3][32][34];              // 13056

    // ---- register-resident B fragments (verified layout) ----
    const int jgB = b * 32 + s31;
    bf16x8 Bf[56];
    {
        const float* Rrow = R + (size_t)(w * H_ + jgB) * H_;
        #pragma unroll
        for (int c = 0; c < 56; ++c) {
            const float4 p0 = *(const float4*)(Rrow + 16*c + 4*hi);
            const float4 p1 = *(const float4*)(Rrow + 16*c + 8 + 4*hi);
            bf16x8 f;
            f[0]=(short)f2bf(p0.x); f[1]=(short)f2bf(p0.y);
            f[2]=(short)f2bf(p0.z); f[3]=(short)f2bf(p0.w);
            f[4]=(short)f2bf(p1.x); f[5]=(short)f2bf(p1.y);
            f[6]=(short)f2bf(p1.z); f[7]=(short)f2bf(p1.w);
            Bf[c] = f;
        }
    }

    // ---- gate-thread constants (tid<128): 2 j x 4 s per thread ----
    const int jp  = tid & 15;
    const int sg  = (tid >> 4) & 7;
    const int j0  = 2 * jp;
    const int jg0 = b * 32 + j0;
    float wu[2][3], wr[2][3], we[2][3], gb[2][3];
    float hreg[4][2];
    if (tid < 128) {
        #pragma unroll
        for (int jj = 0; jj < 2; ++jj) {
            const int jg = jg0 + jj;
            if (jg < SUB_) {
                wu[jj][0]=Wc[2*jg];            wu[jj][1]=Wc[2*jg+1];            wu[jj][2]=0.f;
                wr[jj][0]=Wc[2*(SUB_+jg)];     wr[jj][1]=Wc[2*(SUB_+jg)+1];     wr[jj][2]=0.f;
                we[jj][0]=Wc[2*(2*SUB_+jg)];   we[jj][1]=Wc[2*(2*SUB_+jg)+1];   we[jj][2]=0.f;
            } else {
                const int jf = jg - SUB_;
                wu[jj][0]=Wf[3*jf];            wu[jj][1]=Wf[3*jf+1];            wu[jj][2]=Wf[3*jf+2];
                wr[jj][0]=Wf[3*(SUB_+jf)];     wr[jj][1]=Wf[3*(SUB_+jf)+1];     wr[jj][2]=Wf[3*(SUB_+jf)+2];
                we[jj][0]=Wf[3*(2*SUB_+jf)];   we[jj][1]=Wf[3*(2*SUB_+jf)+1];   we[jj][2]=Wf[3*(2*SUB_+jf)+2];
            }
            gb[jj][0]=b_u[jg]; gb[jj][1]=b_r[jg]; gb[jj][2]=b_e[jg];
        }
        #pragma unroll
        for (int q = 0; q < 4; ++q) {
            const int s = sg*4 + q;
            hreg[q][0] = state[(size_t)s*H_ + jg0];
            hreg[q][1] = state[(size_t)s*H_ + jg0 + 1];
        }
    }

    const int v4l = lane * 4;
    const char* abb = Abuf + s31*2048 + 8*s31 + 8*hi;   // A-frag base (imm + 32c)

    #pragma unroll 1
    for (int t = 1; t <= T_; ++t) {
        // ---- (A) per-step inputs (issued before spin; latency hidden) ----
        float s0n[4], s1n[4], c0n[4];
        if (tid < 128) {
            const float kn = 2.0f / 255.0f;
            #pragma unroll
            for (int q = 0; q < 4; ++q) {
                const size_t idx = (size_t)(sg*4 + q)*T_ + (size_t)(t - 1);
                const int2 sv = *(const int2*)(sample + idx*2);
                s0n[q] = kn*(float)sv.x - 1.0f;
                s1n[q] = kn*(float)sv.y - 1.0f;
                c0n[q] = kn*(float)cts[idx] - 1.0f;
            }
        }
        // ---- (B) wave 0 polls single epoch counter; others park at barrier ----
        if (w == 0) {
            const int need = 2 * NBLK_ * (t - 1);
            for (;;) {
                int v = __hip_atomic_load(counter, __ATOMIC_RELAXED, __HIP_MEMORY_SCOPE_AGENT);
                if (v >= need) break;
                __builtin_amdgcn_s_sleep(1);
            }
        }
        asm volatile("" ::: "memory");
        __builtin_amdgcn_sched_barrier(0);
        __syncthreads();   // release: all blocks' h(t-1) visible

        // ---- (C) stage h(t-1) rotated into LDS, 4B granularity, coalesced ----
        {
            const char* sb = (t == 1) ? (const char*)h0
                                      : (const char*)states + (size_t)(t - 2)*SLOT_B;
            #pragma unroll
            for (int ii = 0; ii < 86; ++ii) {
                const int i = w + 3*ii;
                if (i < 256) {
                    const int sp = i >> 3;
                    // src = sb + 1792*sp + (o - 8*sp), o = 256*(i&7) + 4*lane
                    gload_lds4(sb + sp*1784 + (i & 7)*256 + v4l, Abuf + i*256);
                }
            }
        }
        __syncthreads();   // (D) staging complete

        // ---- (E) MFMA, dual accumulator chains ----
        f32x16 acc0, acc1;
        #pragma unroll
        for (int e = 0; e < 16; ++e) { acc0[e] = 0.0f; acc1[e] = 0.0f; }
        #pragma unroll
        for (int c2 = 0; c2 < 28; ++c2) {
            {
                const short4 p0 = *(const short4*)(abb + 64*c2);
                const short4 p1 = *(const short4*)(abb + 64*c2 + 16);
                acc0 = __builtin_amdgcn_mfma_f32_32x32x16_bf16(mk8(p0, p1), Bf[2*c2], acc0, 0, 0, 0);
            }
            {
                const short4 p0 = *(const short4*)(abb + 64*c2 + 32);
                const short4 p1 = *(const short4*)(abb + 64*c2 + 48);
                acc1 = __builtin_amdgcn_mfma_f32_32x32x16_bf16(mk8(p0, p1), Bf[2*c2+1], acc1, 0, 0, 0);
            }
        }
        #pragma unroll
        for (int e = 0; e < 16; ++e) {
            const int srow = (e & 3) + 8*(e >> 2) + 4*hi;
            gate_out[w][srow][s31] = acc0[e] + acc1[e];
        }
        __syncthreads();   // (F)

        // ---- (G) gates + h update ----
        if (tid < 128) {
            #pragma unroll
            for (int q = 0; q < 4; ++q) {
                const int s = sg*4 + q;
                const float2 g0 = *(const float2*)&gate_out[0][s][j0];
                const float2 g1 = *(const float2*)&gate_out[1][s][j0];
                const float2 g2 = *(const float2*)&gate_out[2][s][j0];
                unsigned int packed = 0;
                #pragma unroll
                for (int jj = 0; jj < 2; ++jj) {
                    const float ru = jj ? g0.y : g0.x;
                    const float rr = jj ? g1.y : g1.x;
                    const float re = jj ? g2.y : g2.x;
                    const float fu = s0n[q]*wu[jj][0] + s1n[q]*wu[jj][1] + c0n[q]*wu[jj][2];
                    const float fr = s0n[q]*wr[jj][0] + s1n[q]*wr[jj][1] + c0n[q]*wr[jj][2];
                    const float fe = s0n[q]*we[jj][0] + s1n[q]*we[jj][1] + c0n[q]*we[jj][2];
                    const float ut = fsig(ru + fu + gb[jj][0]);
                    const float rt = fsig(rr + fr + gb[jj][1]);
                    const float et = ftanh(rt*re + fe + gb[jj][2]);
                    const float hn = ut*hreg[q][jj] + (1.0f - ut)*et;
                    hreg[q][jj] = hn;
                    packed |= (unsigned int)f2bf(hn) << (16*jj);
                    if (t == T_) out[LAST_OFF + (size_t)s*H_ + jg0 + jj] = hn;
                }
                __hip_atomic_store(
                    (unsigned int*)(states + (size_t)(t-1)*SLOT_E + s*H_ + jg0),
                    packed, __ATOMIC_RELAXED, __HIP_MEMORY_SCOPE_AGENT);
            }
        }
        // ---- (H) per-wave store drain, then one epoch add per storing wave ----
        if (w < 2) {
            asm volatile("s_waitcnt vmcnt(0)" ::: "memory");
            if (lane == 0)
                (void)__hip_atomic_fetch_add(counter, 1, __ATOMIC_RELAXED,
                                             __HIP_MEMORY_SCOPE_AGENT);
        }
    }
}

// ---------------------------------------------------------------------------
// head v3 (MFMA bf16): per block 32 rows; relu(W1 h + b1) -> W2 + b2 -> log_softmax
// ---------------------------------------------------------------------------
__global__ __launch_bounds__(256, 1)
void wavrnn_head3(const unsigned short* __restrict__ states,  // time-major
                  const unsigned short* __restrict__ wb,
                  const float* __restrict__ bc1, const float* __restrict__ bc2,
                  const float* __restrict__ bf1, const float* __restrict__ bf2,
                  float* __restrict__ out)
{
    // rotated rows, pitch 1920, rotation 8*(row&15)
    __shared__ __align__(16) char stL[32 * 1920];   // 61440 (aliased by lg after stage A)
    __shared__ __align__(16) char a1L[32 * 1920];   // 61440

    const int tid  = (int)threadIdx.x;
    const int w    = tid >> 6;
    const int lane = tid & 63;
    const int nl   = lane & 31;
    const int hi   = lane >> 5;
    const int row0 = (int)blockIdx.x * 32;

    // ---- stage states rows (8B pieces, rotated) ----
    #pragma unroll
    for (int ii = 0; ii < 28; ++ii) {
        const int idx = ii*256 + tid;        // 0..7167 = 32 rows x 224 pieces
        const int rp  = idx / 224;
        const int p   = idx - rp*224;
        const int r   = row0 + rp;
        const int sr  = r / 2000;
        const int tr  = r - sr*2000;
        const uint2 v = *(const uint2*)(states + (size_t)tr*SLOT_E + sr*H_ + p*4);
        *(uint2*)(stL + rp*1920 + 8*(rp & 15) + p*8) = v;
    }
    __syncthreads();

    // ---- stage A: a1 = relu(W1 h_half + b1); 28 n-tiles over 4 waves ----
    {
        const char* apb = stL + nl*1920 + 8*(nl & 15) + 8*hi;
        #pragma unroll 1
        for (int tt = 0; tt < 7; ++tt) {
            const int nt   = tt*4 + w;
            const int head = nt >= 14;
            const int jt   = nt - head*14;
            const int orow = jt*32 + nl;                     // 0..447
            const unsigned short* wrp = wb + (head ? WB_W1F : WB_W1C) + (size_t)orow*448;
            const float bias = (head ? bf1 : bc1)[orow];
            const int ko = head * 896;
            f32x16 acc;
            #pragma unroll
            for (int e = 0; e < 16; ++e) acc[e] = bias;
            #pragma unroll
            for (int c = 0; c < 28; ++c) {
                const short4 a0 = *(const short4*)(apb + ko + 32*c);
                const short4 a1 = *(const short4*)(apb + ko + 32*c + 16);
                const short4 b0 = *(const short4*)((const char*)wrp + 32*c + 8*hi);
                const short4 b1 = *(const short4*)((const char*)wrp + 32*c + 8*hi + 16);
                acc = __builtin_amdgcn_mfma_f32_32x32x16_bf16(mk8(a0, a1), mk8(b0, b1), acc, 0, 0, 0);
            }
            const int jg = head*448 + jt*32 + nl;
            #pragma unroll
            for (int e = 0; e < 16; ++e) {
                const int m2 = (e & 3) + 8*(e >> 2) + 4*hi;
                *(unsigned short*)(a1L + m2*1920 + 8*(m2 & 15) + 2*jg) =
                    f2bf(fmaxf(acc[e], 0.0f));
            }
        }
    }
    __syncthreads();

    // ---- stage B: logits = W2 a1_half + b2 -> lg (bf16, aliases stL) ----
    {
        unsigned short* lg = (unsigned short*)stL;    // [32][520]
        const char* apb = a1L + nl*1920 + 8*(nl & 15) + 8*hi;
        #pragma unroll 1
        for (int tt = 0; tt < 4; ++tt) {
            const int nt   = tt*4 + w;
            const int head = nt >= 8;
            const int ct   = (nt & 7)*32 + nl;               // 0..255
            const unsigned short* wrp = wb + (head ? WB_W2F : WB_W2C) + (size_t)ct*448;
            const float bias = (head ? bf2 : bc2)[ct];
            const int ko = head * 896;
            f32x16 acc;
            #pragma unroll
            for (int e = 0; e < 16; ++e) acc[e] = bias;
            #pragma unroll
            for (int c = 0; c < 28; ++c) {
                const short4 a0 = *(const short4*)(apb + ko + 32*c);
                const short4 a1 = *(const short4*)(apb + ko + 32*c + 16);
                const short4 b0 = *(const short4*)((const char*)wrp + 32*c + 8*hi);
                const short4 b1 = *(const short4*)((const char*)wrp + 32*c + 8*hi + 16);
                acc = __builtin_amdgcn_mfma_f32_32x32x16_bf16(mk8(a0, a1), mk8(b0, b1), acc, 0, 0, 0);
            }
            #pragma unroll
            for (int e = 0; e < 16; ++e) {
                const int m2 = (e & 3) + 8*(e >> 2) + 4*hi;
                lg[m2*520 + head*256 + (nt & 7)*32 + nl] = f2bf(acc[e]);
            }
        }
    }
    __syncthreads();

    // ---- log_softmax per (head,row) ----
    {
        const unsigned short* lg = (const unsigned short*)stL;
        #pragma unroll 1
        for (int p = w; p < 64; p += 4) {
            const int hh = p >> 5;
            const int rr = p & 31;
            const ushort4 lv = *(const ushort4*)(lg + rr*520 + hh*256 + 4*lane);
            const float v0 = bf2f(lv.x), v1 = bf2f(lv.y), v2 = bf2f(lv.z), v3 = bf2f(lv.w);
            float m = fmaxf(fmaxf(v0, v1), fmaxf(v2, v3));
            #pragma unroll
            for (int d = 1; d < 64; d <<= 1) m = fmaxf(m, __shfl_xor(m, d));
            float sm = __expf(v0-m) + __expf(v1-m) + __expf(v2-m) + __expf(v3-m);
            #pragma unroll
            for (int d = 1; d < 64; d <<= 1) sm += __shfl_xor(sm, d);
            const float ls = m + __logf(sm);
            float* o = out + (hh ? (size_t)FT_OFF : (size_t)0) + (size_t)(row0 + rr)*Q_ + 4*lane;
            o[0] = v0 - ls; o[1] = v1 - ls; o[2] = v2 - ls; o[3] = v3 - ls;
        }
    }
}

// ---------------------------------------------------------------------------
extern "C" void kernel_launch(void* const* d_in, const int* in_sizes, int n_in,
                              void* d_out, int out_size, void* d_ws, size_t ws_size,
                              hipStream_t stream) {
    (void)in_sizes; (void)n_in; (void)out_size; (void)ws_size;
    const int*   sample = (const int*)d_in[0];
    const int*   cts    = (const int*)d_in[1];
    const float* state  = (const float*)d_in[2];
    const float* R      = (const float*)d_in[3];
    const float* Wc     = (const float*)d_in[4];
    const float* Wf     = (const float*)d_in[5];
    const float* b_u    = (const float*)d_in[6];
    const float* b_r    = (const float*)d_in[7];
    const float* b_e    = (const float*)d_in[8];
    const float* Wc1    = (const float*)d_in[9];
    const float* bc1    = (const float*)d_in[10];
    const float* Wc2    = (const float*)d_in[11];
    const float* bc2    = (const float*)d_in[12];
    const float* Wf1    = (const float*)d_in[13];
    const float* bf1    = (const float*)d_in[14];
    const float* Wf2    = (const float*)d_in[15];
    const float* bf2    = (const float*)d_in[16];

    float* out = (float*)d_out;
    int*            counter = (int*)((char*)d_ws + WS_FLAGS);
    unsigned short* h0      = (unsigned short*)((char*)d_ws + WS_H0);
    unsigned short* wb      = (unsigned short*)((char*)d_ws + WS_WB);
    unsigned short* states  = (unsigned short*)((char*)d_ws + WS_STATES);

    wavrnn_prep<<<2464, 256, 0, stream>>>(state, Wc1, Wf1, Wc2, Wf2, wb, h0, counter);
    wavrnn_scan4<<<NBLK_, 192, 0, stream>>>(sample, cts, state, R, Wc, Wf,
                                            b_u, b_r, b_e, h0, counter, states, out);
    wavrnn_head3<<<(B_ * T_) / 32, 256, 0, stream>>>(states, wb, bc1, bc2, bf1, bf2, out);
}

// Round 5
// 11262.538 us; speedup vs baseline: 1.9968x; 1.9483x over previous
//
#include <hip/hip_runtime.h>
#include <hip/hip_bf16.h>

// Problem constants
#define B_   32
#define T_   2000
#define H_   896
#define SUB_ 448
#define Q_   256

// d_out layout (floats): ct [32,2000,256], ft [32,2000,256], last [32,1,896]
#define FT_OFF   16384000
#define LAST_OFF 32768000

// scan decomposition: 28 blocks x 192 threads (3 waves, 1 wave/SIMD)
#define NBLK_ 28

// d_ws layout (bytes)
//   flags  : [56] ints padded x32 (128B apart)        @ 0       (7168 B)
//   h0     : bf16 [32][896]                           @ 8192    (57344 B)
//   Wb     : bf16 W1c|W1f|W2c|W2f                     @ 65536   (1261568 B)
//   states : bf16 time-major [2000][32][896]          @ 1327104 (114688000 B)
#define WS_FLAGS  0
#define WS_H0     8192
#define WS_WB     65536
#define WS_STATES 1327104

// Wb element offsets (ushort units)
#define WB_W1C 0
#define WB_W1F 200704
#define WB_W2C 401408
#define WB_W2F 516096
#define WB_N   630784

#define SLOT_B 57344   // bytes per states time-slot (32*896*2)
#define SLOT_E 28672   // ushort elems per slot

typedef __attribute__((ext_vector_type(8)))  short bf16x8;
typedef __attribute__((ext_vector_type(16))) float f32x16;

__device__ __forceinline__ unsigned short f2bf(float f) {
    unsigned int u = __builtin_bit_cast(unsigned int, f);
    u += 0x7fff + ((u >> 16) & 1);          // RNE
    return (unsigned short)(u >> 16);
}
__device__ __forceinline__ float bf2f(unsigned short u) {
    return __builtin_bit_cast(float, (unsigned int)u << 16);
}
__device__ __forceinline__ void gload_lds16(const void* g, void* l) {
    __builtin_amdgcn_global_load_lds(
        (const __attribute__((address_space(1))) unsigned int*)g,
        (__attribute__((address_space(3))) unsigned int*)l, 16, 0, 0);
}
__device__ __forceinline__ bf16x8 mk8(short4 a, short4 b) {
    bf16x8 f;
    f[0]=a.x; f[1]=a.y; f[2]=a.z; f[3]=a.w;
    f[4]=b.x; f[5]=b.y; f[6]=b.z; f[7]=b.w;
    return f;
}
__device__ __forceinline__ float fsig(float x) {
    return __builtin_amdgcn_rcpf(1.0f + __expf(-x));
}
__device__ __forceinline__ float ftanh(float x) {
    float xc = fminf(fmaxf(x, -9.0f), 9.0f);
    float z  = __expf(2.0f * xc);
    return 1.0f - 2.0f * __builtin_amdgcn_rcpf(z + 1.0f);
}

// ---------------------------------------------------------------------------
// prep: flags=0, h0=bf16(state), Wb=bf16(W1c|W1f|W2c|W2f)
// ---------------------------------------------------------------------------
__global__ void wavrnn_prep(const float* __restrict__ state,
                            const float* __restrict__ Wc1, const float* __restrict__ Wf1,
                            const float* __restrict__ Wc2, const float* __restrict__ Wf2,
                            unsigned short* __restrict__ wb,
                            unsigned short* __restrict__ h0,
                            int* __restrict__ flags) {
    const int i = blockIdx.x * 256 + threadIdx.x;
    if (i < WB_N) {
        float v;
        if      (i < WB_W1F) v = Wc1[i];
        else if (i < WB_W2C) v = Wf1[i - WB_W1F];
        else if (i < WB_W2F) v = Wc2[i - WB_W2C];
        else                 v = Wf2[i - WB_W2F];
        wb[i] = f2bf(v);
    }
    if (i < 1792) flags[i] = 0;
    if (i < B_ * H_) h0[i] = f2bf(state[i]);
}

// ---------------------------------------------------------------------------
// scan v5: rotated conflict-free LDS + 64x16B fully-coalesced LDS-DMA staging
// (rotation folded into scalar source base), v2-topology sync without fence.
// ---------------------------------------------------------------------------
__global__ __launch_bounds__(192, 1)
void wavrnn_scan5(const int* __restrict__ sample, const int* __restrict__ cts,
                  const float* __restrict__ state, const float* __restrict__ R,
                  const float* __restrict__ Wc, const float* __restrict__ Wf,
                  const float* __restrict__ b_u, const float* __restrict__ b_r,
                  const float* __restrict__ b_e,
                  const unsigned short* __restrict__ h0,
                  int* __restrict__ flags,
                  unsigned short* __restrict__ states,   // time-major [2000][32][896]
                  float* __restrict__ out)
{
    const int tid  = (int)threadIdx.x;
    const int w    = tid >> 6;        // wave = gate (0:u, 1:r, 2:e)
    const int lane = tid & 63;
    const int s31  = lane & 31;
    const int hi   = lane >> 5;
    const int b    = (int)blockIdx.x;

    // rotated h tile: row s at [s*2048, +2048); element k at byte 8*s + 2*k
    __shared__ __align__(16) char Abuf[32 * 2048];     // 65536
    __shared__ float gate_out[3][32][34];              // 13056

    // ---- register-resident B fragments (verified layout) ----
    const int jgB = b * 32 + s31;
    bf16x8 Bf[56];
    {
        const float* Rrow = R + (size_t)(w * H_ + jgB) * H_;
        #pragma unroll
        for (int c = 0; c < 56; ++c) {
            const float4 p0 = *(const float4*)(Rrow + 16*c + 4*hi);
            const float4 p1 = *(const float4*)(Rrow + 16*c + 8 + 4*hi);
            bf16x8 f;
            f[0]=(short)f2bf(p0.x); f[1]=(short)f2bf(p0.y);
            f[2]=(short)f2bf(p0.z); f[3]=(short)f2bf(p0.w);
            f[4]=(short)f2bf(p1.x); f[5]=(short)f2bf(p1.y);
            f[6]=(short)f2bf(p1.z); f[7]=(short)f2bf(p1.w);
            Bf[c] = f;
        }
    }

    // ---- gate-thread constants (tid<128): 2 j x 4 s per thread ----
    const int jp  = tid & 15;
    const int sg  = (tid >> 4) & 7;
    const int j0  = 2 * jp;
    const int jg0 = b * 32 + j0;
    float wu[2][3], wr[2][3], we[2][3], gb[2][3];
    float hreg[4][2];
    if (tid < 128) {
        #pragma unroll
        for (int jj = 0; jj < 2; ++jj) {
            const int jg = jg0 + jj;
            if (jg < SUB_) {
                wu[jj][0]=Wc[2*jg];            wu[jj][1]=Wc[2*jg+1];            wu[jj][2]=0.f;
                wr[jj][0]=Wc[2*(SUB_+jg)];     wr[jj][1]=Wc[2*(SUB_+jg)+1];     wr[jj][2]=0.f;
                we[jj][0]=Wc[2*(2*SUB_+jg)];   we[jj][1]=Wc[2*(2*SUB_+jg)+1];   we[jj][2]=0.f;
            } else {
                const int jf = jg - SUB_;
                wu[jj][0]=Wf[3*jf];            wu[jj][1]=Wf[3*jf+1];            wu[jj][2]=Wf[3*jf+2];
                wr[jj][0]=Wf[3*(SUB_+jf)];     wr[jj][1]=Wf[3*(SUB_+jf)+1];     wr[jj][2]=Wf[3*(SUB_+jf)+2];
                we[jj][0]=Wf[3*(2*SUB_+jf)];   we[jj][1]=Wf[3*(2*SUB_+jf)+1];   we[jj][2]=Wf[3*(2*SUB_+jf)+2];
            }
            gb[jj][0]=b_u[jg]; gb[jj][1]=b_r[jg]; gb[jj][2]=b_e[jg];
        }
        #pragma unroll
        for (int q = 0; q < 4; ++q) {
            const int s = sg*4 + q;
            hreg[q][0] = state[(size_t)s*H_ + jg0];
            hreg[q][1] = state[(size_t)s*H_ + jg0 + 1];
        }
    }

    const int v16l = lane * 16;
    const char* abb = Abuf + s31*2048 + 8*s31 + 8*hi;   // A-frag base (imm + 64*c2)

    #pragma unroll 1
    for (int t = 1; t <= T_; ++t) {
        // ---- (A) per-step inputs (issued before spin; latency hidden) ----
        float s0n[4], s1n[4], c0n[4];
        if (tid < 128) {
            const float kn = 2.0f / 255.0f;
            #pragma unroll
            for (int q = 0; q < 4; ++q) {
                const size_t idx = (size_t)(sg*4 + q)*T_ + (size_t)(t - 1);
                const int2 sv = *(const int2*)(sample + idx*2);
                s0n[q] = kn*(float)sv.x - 1.0f;
                s1n[q] = kn*(float)sv.y - 1.0f;
                c0n[q] = kn*(float)cts[idx] - 1.0f;
            }
        }
        // ---- (B) wave 0 polls 56 padded flag lines in one vector load ----
        if (w == 0) {
            for (;;) {
                int v = (lane < 2*NBLK_)
                    ? __hip_atomic_load(&flags[lane*32], __ATOMIC_RELAXED, __HIP_MEMORY_SCOPE_AGENT)
                    : 0x7fffffff;
                if (__all(v >= t - 1)) break;
                __builtin_amdgcn_s_sleep(1);
            }
        }
        asm volatile("" ::: "memory");
        __builtin_amdgcn_sched_barrier(0);
        __syncthreads();   // release: all blocks' h(t-1) visible

        // ---- (C) stage h(t-1): 64 x 16B, contiguous 1KB per issue ----
        // LDS dest (uniform) = Abuf + sp*2048 + half*1024 (+ lane*16 by HW)
        // src = sb + sp*1784 + half*1024 + 16*lane  (rotation folded in base)
        {
            const char* sb = (t == 1) ? (const char*)h0
                                      : (const char*)states + (size_t)(t - 2)*SLOT_B;
            #pragma unroll
            for (int ii = 0; ii < 22; ++ii) {
                const int i = w + 3*ii;
                if (i < 64) {
                    const int sp   = i >> 1;
                    const int half = i & 1;
                    gload_lds16(sb + sp*1784 + half*1024 + v16l,
                                Abuf + sp*2048 + half*1024);
                }
            }
        }
        __syncthreads();   // (D) staging complete

        // ---- (E) MFMA, dual accumulator chains ----
        f32x16 acc0, acc1;
        #pragma unroll
        for (int e = 0; e < 16; ++e) { acc0[e] = 0.0f; acc1[e] = 0.0f; }
        #pragma unroll
        for (int c2 = 0; c2 < 28; ++c2) {
            {
                const short4 p0 = *(const short4*)(abb + 64*c2);
                const short4 p1 = *(const short4*)(abb + 64*c2 + 16);
                acc0 = __builtin_amdgcn_mfma_f32_32x32x16_bf16(mk8(p0, p1), Bf[2*c2], acc0, 0, 0, 0);
            }
            {
                const short4 p0 = *(const short4*)(abb + 64*c2 + 32);
                const short4 p1 = *(const short4*)(abb + 64*c2 + 48);
                acc1 = __builtin_amdgcn_mfma_f32_32x32x16_bf16(mk8(p0, p1), Bf[2*c2+1], acc1, 0, 0, 0);
            }
        }
        #pragma unroll
        for (int e = 0; e < 16; ++e) {
            const int srow = (e & 3) + 8*(e >> 2) + 4*hi;
            gate_out[w][srow][s31] = acc0[e] + acc1[e];
        }
        __syncthreads();   // (F)

        // ---- (G) gates + h update ----
        if (tid < 128) {
            #pragma unroll
            for (int q = 0; q < 4; ++q) {
                const int s = sg*4 + q;
                const float2 g0 = *(const float2*)&gate_out[0][s][j0];
                const float2 g1 = *(const float2*)&gate_out[1][s][j0];
                const float2 g2 = *(const float2*)&gate_out[2][s][j0];
                unsigned int packed = 0;
                #pragma unroll
                for (int jj = 0; jj < 2; ++jj) {
                    const float ru = jj ? g0.y : g0.x;
                    const float rr = jj ? g1.y : g1.x;
                    const float re = jj ? g2.y : g2.x;
                    const float fu = s0n[q]*wu[jj][0] + s1n[q]*wu[jj][1] + c0n[q]*wu[jj][2];
                    const float fr = s0n[q]*wr[jj][0] + s1n[q]*wr[jj][1] + c0n[q]*wr[jj][2];
                    const float fe = s0n[q]*we[jj][0] + s1n[q]*we[jj][1] + c0n[q]*we[jj][2];
                    const float ut = fsig(ru + fu + gb[jj][0]);
                    const float rt = fsig(rr + fr + gb[jj][1]);
                    const float et = ftanh(rt*re + fe + gb[jj][2]);
                    const float hn = ut*hreg[q][jj] + (1.0f - ut)*et;
                    hreg[q][jj] = hn;
                    packed |= (unsigned int)f2bf(hn) << (16*jj);
                    if (t == T_) out[LAST_OFF + (size_t)s*H_ + jg0 + jj] = hn;
                }
                __hip_atomic_store(
                    (unsigned int*)(states + (size_t)(t-1)*SLOT_E + s*H_ + jg0),
                    packed, __ATOMIC_RELAXED, __HIP_MEMORY_SCOPE_AGENT);
            }
        }
        // ---- (H) per-wave store drain, then per-wave flag ----
        if (w < 2) {
            asm volatile("s_waitcnt vmcnt(0)" ::: "memory");
            if (lane == 0)
                __hip_atomic_store(&flags[(2*b + w)*32], t,
                                   __ATOMIC_RELAXED, __HIP_MEMORY_SCOPE_AGENT);
        }
    }
}

// ---------------------------------------------------------------------------
// head v3 (MFMA bf16): per block 32 rows; relu(W1 h + b1) -> W2 + b2 -> log_softmax
// ---------------------------------------------------------------------------
__global__ __launch_bounds__(256, 1)
void wavrnn_head3(const unsigned short* __restrict__ states,  // time-major
                  const unsigned short* __restrict__ wb,
                  const float* __restrict__ bc1, const float* __restrict__ bc2,
                  const float* __restrict__ bf1, const float* __restrict__ bf2,
                  float* __restrict__ out)
{
    // rotated rows, pitch 1920, rotation 8*(row&15)
    __shared__ __align__(16) char stL[32 * 1920];   // 61440 (aliased by lg after stage A)
    __shared__ __align__(16) char a1L[32 * 1920];   // 61440

    const int tid  = (int)threadIdx.x;
    const int w    = tid >> 6;
    const int lane = tid & 63;
    const int nl   = lane & 31;
    const int hi   = lane >> 5;
    const int row0 = (int)blockIdx.x * 32;

    // ---- stage states rows (8B pieces, rotated) ----
    #pragma unroll
    for (int ii = 0; ii < 28; ++ii) {
        const int idx = ii*256 + tid;        // 0..7167 = 32 rows x 224 pieces
        const int rp  = idx / 224;
        const int p   = idx - rp*224;
        const int r   = row0 + rp;
        const int sr  = r / 2000;
        const int tr  = r - sr*2000;
        const uint2 v = *(const uint2*)(states + (size_t)tr*SLOT_E + sr*H_ + p*4);
        *(uint2*)(stL + rp*1920 + 8*(rp & 15) + p*8) = v;
    }
    __syncthreads();

    // ---- stage A: a1 = relu(W1 h_half + b1); 28 n-tiles over 4 waves ----
    {
        const char* apb = stL + nl*1920 + 8*(nl & 15) + 8*hi;
        #pragma unroll 1
        for (int tt = 0; tt < 7; ++tt) {
            const int nt   = tt*4 + w;
            const int head = nt >= 14;
            const int jt   = nt - head*14;
            const int orow = jt*32 + nl;                     // 0..447
            const unsigned short* wrp = wb + (head ? WB_W1F : WB_W1C) + (size_t)orow*448;
            const float bias = (head ? bf1 : bc1)[orow];
            const int ko = head * 896;
            f32x16 acc;
            #pragma unroll
            for (int e = 0; e < 16; ++e) acc[e] = bias;
            #pragma unroll
            for (int c = 0; c < 28; ++c) {
                const short4 a0 = *(const short4*)(apb + ko + 32*c);
                const short4 a1 = *(const short4*)(apb + ko + 32*c + 16);
                const short4 b0 = *(const short4*)((const char*)wrp + 32*c + 8*hi);
                const short4 b1 = *(const short4*)((const char*)wrp + 32*c + 8*hi + 16);
                acc = __builtin_amdgcn_mfma_f32_32x32x16_bf16(mk8(a0, a1), mk8(b0, b1), acc, 0, 0, 0);
            }
            const int jg = head*448 + jt*32 + nl;
            #pragma unroll
            for (int e = 0; e < 16; ++e) {
                const int m2 = (e & 3) + 8*(e >> 2) + 4*hi;
                *(unsigned short*)(a1L + m2*1920 + 8*(m2 & 15) + 2*jg) =
                    f2bf(fmaxf(acc[e], 0.0f));
            }
        }
    }
    __syncthreads();

    // ---- stage B: logits = W2 a1_half + b2 -> lg (bf16, aliases stL) ----
    {
        unsigned short* lg = (unsigned short*)stL;    // [32][520]
        const char* apb = a1L + nl*1920 + 8*(nl & 15) + 8*hi;
        #pragma unroll 1
        for (int tt = 0; tt < 4; ++tt) {
            const int nt   = tt*4 + w;
            const int head = nt >= 8;
            const int ct   = (nt & 7)*32 + nl;               // 0..255
            const unsigned short* wrp = wb + (head ? WB_W2F : WB_W2C) + (size_t)ct*448;
            const float bias = (head ? bf2 : bc2)[ct];
            const int ko = head * 896;
            f32x16 acc;
            #pragma unroll
            for (int e = 0; e < 16; ++e) acc[e] = bias;
            #pragma unroll
            for (int c = 0; c < 28; ++c) {
                const short4 a0 = *(const short4*)(apb + ko + 32*c);
                const short4 a1 = *(const short4*)(apb + ko + 32*c + 16);
                const short4 b0 = *(const short4*)((const char*)wrp + 32*c + 8*hi);
                const short4 b1 = *(const short4*)((const char*)wrp + 32*c + 8*hi + 16);
                acc = __builtin_amdgcn_mfma_f32_32x32x16_bf16(mk8(a0, a1), mk8(b0, b1), acc, 0, 0, 0);
            }
            #pragma unroll
            for (int e = 0; e < 16; ++e) {
                const int m2 = (e & 3) + 8*(e >> 2) + 4*hi;
                lg[m2*520 + head*256 + (nt & 7)*32 + nl] = f2bf(acc[e]);
            }
        }
    }
    __syncthreads();

    // ---- log_softmax per (head,row) ----
    {
        const unsigned short* lg = (const unsigned short*)stL;
        #pragma unroll 1
        for (int p = w; p < 64; p += 4) {
            const int hh = p >> 5;
            const int rr = p & 31;
            const ushort4 lv = *(const ushort4*)(lg + rr*520 + hh*256 + 4*lane);
            const float v0 = bf2f(lv.x), v1 = bf2f(lv.y), v2 = bf2f(lv.z), v3 = bf2f(lv.w);
            float m = fmaxf(fmaxf(v0, v1), fmaxf(v2, v3));
            #pragma unroll
            for (int d = 1; d < 64; d <<= 1) m = fmaxf(m, __shfl_xor(m, d));
            float sm = __expf(v0-m) + __expf(v1-m) + __expf(v2-m) + __expf(v3-m);
            #pragma unroll
            for (int d = 1; d < 64; d <<= 1) sm += __shfl_xor(sm, d);
            const float ls = m + __logf(sm);
            float* o = out + (hh ? (size_t)FT_OFF : (size_t)0) + (size_t)(row0 + rr)*Q_ + 4*lane;
            o[0] = v0 - ls; o[1] = v1 - ls; o[2] = v2 - ls; o[3] = v3 - ls;
        }
    }
}

// ---------------------------------------------------------------------------
extern "C" void kernel_launch(void* const* d_in, const int* in_sizes, int n_in,
                              void* d_out, int out_size, void* d_ws, size_t ws_size,
                              hipStream_t stream) {
    (void)in_sizes; (void)n_in; (void)out_size; (void)ws_size;
    const int*   sample = (const int*)d_in[0];
    const int*   cts    = (const int*)d_in[1];
    const float* state  = (const float*)d_in[2];
    const float* R      = (const float*)d_in[3];
    const float* Wc     = (const float*)d_in[4];
    const float* Wf     = (const float*)d_in[5];
    const float* b_u    = (const float*)d_in[6];
    const float* b_r    = (const float*)d_in[7];
    const float* b_e    = (const float*)d_in[8];
    const float* Wc1    = (const float*)d_in[9];
    const float* bc1    = (const float*)d_in[10];
    const float* Wc2    = (const float*)d_in[11];
    const float* bc2    = (const float*)d_in[12];
    const float* Wf1    = (const float*)d_in[13];
    const float* bf1    = (const float*)d_in[14];
    const float* Wf2    = (const float*)d_in[15];
    const float* bf2    = (const float*)d_in[16];

    float* out = (float*)d_out;
    int*            flags  = (int*)((char*)d_ws + WS_FLAGS);
    unsigned short* h0     = (unsigned short*)((char*)d_ws + WS_H0);
    unsigned short* wb     = (unsigned short*)((char*)d_ws + WS_WB);
    unsigned short* states = (unsigned short*)((char*)d_ws + WS_STATES);

    wavrnn_prep<<<2464, 256, 0, stream>>>(state, Wc1, Wf1, Wc2, Wf2, wb, h0, flags);
    wavrnn_scan5<<<NBLK_, 192, 0, stream>>>(sample, cts, state, R, Wc, Wf,
                                            b_u, b_r, b_e, h0, flags, states, out);
    wavrnn_head3<<<(B_ * T_) / 32, 256, 0, stream>>>(states, wb, bc1, bc2, bf1, bf2, out);
}